// Round 1
// baseline (334.869 us; speedup 1.0000x reference)
//
#include <hip/hip_runtime.h>

typedef _Float16 half8 __attribute__((ext_vector_type(8)));
typedef _Float16 half4 __attribute__((ext_vector_type(4)));
typedef float f32x4 __attribute__((ext_vector_type(4)));

#define N_B 2
#define S_LEN 2048
#define NH 16
#define HD 64
#define DM 1024

// ---------------------------------------------------------------------------
// Prep 1: convert f32 [n][s][h*64+d] -> f16 [n][h][s][d]   (Q and K)
// ---------------------------------------------------------------------------
__global__ __launch_bounds__(256) void k_regroup(const float* __restrict__ in,
                                                 _Float16* __restrict__ out,
                                                 int n4) {
    int i = blockIdx.x * blockDim.x + threadIdx.x;
    if (i >= n4) return;
    float4 v = ((const float4*)in)[i];
    int base = i * 4;
    int d = base & 63;
    int h = (base >> 6) & 15;
    int s = (base >> 10) & 2047;
    int n = base >> 21;
    size_t o = ((size_t)((n * NH + h) * S_LEN + s)) * HD + d;
    half4 hv = {(_Float16)v.x, (_Float16)v.y, (_Float16)v.z, (_Float16)v.w};
    *(half4*)(out + o) = hv;
}

// ---------------------------------------------------------------------------
// Prep 2: V f32 [n][s][h*64+d] -> Vt f16 [n][h][d][s]  (LDS transpose, 64x64)
// ---------------------------------------------------------------------------
__global__ __launch_bounds__(256) void k_vt(const float* __restrict__ V,
                                            _Float16* __restrict__ Vt) {
    __shared__ _Float16 tile[64][65];
    int st = blockIdx.x, h = blockIdx.y, n = blockIdx.z;
    int c = threadIdx.x & 63, r0 = threadIdx.x >> 6;  // r0: 0..3
#pragma unroll
    for (int i = 0; i < 16; ++i) {
        int r = i * 4 + r0;
        tile[r][c] = (_Float16)V[((size_t)(n * S_LEN) + st * 64 + r) * DM + h * HD + c];
    }
    __syncthreads();
#pragma unroll
    for (int i = 0; i < 16; ++i) {
        int d = i * 4 + r0;
        Vt[((size_t)((n * NH + h) * HD + d)) * S_LEN + st * 64 + c] = tile[c][d];
    }
}

// ---------------------------------------------------------------------------
// Prep 3: flat f32 -> f16 convert (W_out, layout [o][i] kept)
// ---------------------------------------------------------------------------
__global__ __launch_bounds__(256) void k_cvt(const float* __restrict__ in,
                                             _Float16* __restrict__ out, int n4) {
    int i = blockIdx.x * blockDim.x + threadIdx.x;
    if (i >= n4) return;
    float4 v = ((const float4*)in)[i];
    half4 hv = {(_Float16)v.x, (_Float16)v.y, (_Float16)v.z, (_Float16)v.w};
    *(half4*)(out + (size_t)i * 4) = hv;
}

// ---------------------------------------------------------------------------
// Flash attention: grid (32 qtiles, 32 n*h), 256 thr = 4 waves x 16 q-rows
// ---------------------------------------------------------------------------
__device__ __forceinline__ int swz(int b) { return b ^ (((b >> 7) & 7) << 4); }

__global__ __launch_bounds__(256) void k_attn(const _Float16* __restrict__ Qh,
                                              const _Float16* __restrict__ Kh,
                                              const _Float16* __restrict__ Vt,
                                              _Float16* __restrict__ Oatt) {
    __shared__ _Float16 Plds[4][16 * 64];
    const int nh = blockIdx.y;     // n*16 + h
    const int qt = blockIdx.x;     // q tile of 64
    const int tid = threadIdx.x;
    const int w = tid >> 6;
    const int lane = tid & 63;
    const int lr = lane & 15;
    const int lg = lane >> 4;

    const size_t head = (size_t)nh * S_LEN * HD;   // same offset for Qh/Kh/Vt
    const _Float16* qp = Qh + head + (size_t)(qt * 64 + w * 16 + lr) * HD + lg * 8;
    half8 qf0 = *(const half8*)(qp);
    half8 qf1 = *(const half8*)(qp + 32);
    const _Float16* kbase = Kh + head + (size_t)lr * HD + lg * 8;
    const _Float16* vbase = Vt + head + (size_t)lr * S_LEN + lg * 8;

    f32x4 zero = {0.f, 0.f, 0.f, 0.f};
    f32x4 oacc[4] = {zero, zero, zero, zero};
    float m_i[4], l_i[4];
#pragma unroll
    for (int i = 0; i < 4; ++i) { m_i[i] = -1e30f; l_i[i] = 0.f; }

    char* pl = (char*)&Plds[w][0];

    for (int kt = 0; kt < S_LEN / 64; ++kt) {
        // ---- S = Q K^T (16 q-rows x 64 keys) ----
        f32x4 s[4] = {zero, zero, zero, zero};
#pragma unroll
        for (int nb = 0; nb < 4; ++nb) {
            const _Float16* kp = kbase + (size_t)(kt * 64 + nb * 16) * HD;
            half8 kf0 = *(const half8*)(kp);
            half8 kf1 = *(const half8*)(kp + 32);
            s[nb] = __builtin_amdgcn_mfma_f32_16x16x32_f16(qf0, kf0, s[nb], 0, 0, 0);
            s[nb] = __builtin_amdgcn_mfma_f32_16x16x32_f16(qf1, kf1, s[nb], 0, 0, 0);
        }
        // ---- online softmax (per q-row; row i lives on 16 lanes of this group)
#pragma unroll
        for (int i = 0; i < 4; ++i) {
            float rm = fmaxf(fmaxf(s[0][i], s[1][i]), fmaxf(s[2][i], s[3][i]));
#pragma unroll
            for (int o = 1; o < 16; o <<= 1) rm = fmaxf(rm, __shfl_xor(rm, o));
            float mn = fmaxf(m_i[i], rm);
            float sc = __expf(m_i[i] - mn);
            m_i[i] = mn;
            float rs = 0.f;
#pragma unroll
            for (int nb = 0; nb < 4; ++nb) {
                float p = __expf(s[nb][i] - mn);
                s[nb][i] = p;
                rs += p;
            }
#pragma unroll
            for (int o = 1; o < 16; o <<= 1) rs += __shfl_xor(rs, o);
            l_i[i] = l_i[i] * sc + rs;
#pragma unroll
            for (int ob = 0; ob < 4; ++ob) oacc[ob][i] *= sc;
        }
        // ---- P -> LDS (f16, [q][k] with XOR swizzle, row stride 128B) ----
#pragma unroll
        for (int nb = 0; nb < 4; ++nb)
#pragma unroll
            for (int i = 0; i < 4; ++i)
                *(_Float16*)(pl + swz((lg * 4 + i) * 128 + (nb * 16 + lr) * 2)) =
                    (_Float16)s[nb][i];
        __syncthreads();
        // ---- O += P V ----
        half8 pa0 = *(const half8*)(pl + swz(lr * 128 + lg * 16));
        half8 pa1 = *(const half8*)(pl + swz(lr * 128 + 64 + lg * 16));
#pragma unroll
        for (int ob = 0; ob < 4; ++ob) {
            const _Float16* vp = vbase + (size_t)(ob * 16) * S_LEN + kt * 64;
            half8 vf0 = *(const half8*)(vp);
            half8 vf1 = *(const half8*)(vp + 32);
            oacc[ob] = __builtin_amdgcn_mfma_f32_16x16x32_f16(pa0, vf0, oacc[ob], 0, 0, 0);
            oacc[ob] = __builtin_amdgcn_mfma_f32_16x16x32_f16(pa1, vf1, oacc[ob], 0, 0, 0);
        }
        __syncthreads();
    }
    // ---- epilogue: Oatt[n][q][h*64+d] = oacc / l ----
    const int n = nh >> 4, h = nh & 15;
#pragma unroll
    for (int i = 0; i < 4; ++i) {
        float inv = 1.f / l_i[i];
        int q = qt * 64 + w * 16 + lg * 4 + i;
#pragma unroll
        for (int ob = 0; ob < 4; ++ob) {
            int d = ob * 16 + lr;
            Oatt[((size_t)(n * S_LEN + q)) * DM + h * HD + d] = (_Float16)(oacc[ob][i] * inv);
        }
    }
}

// ---------------------------------------------------------------------------
// Projection: out[m][o] = sum_i A[m][i] * W[o][i] + b[o]   (M=4096,O=1024,K=1024)
// ---------------------------------------------------------------------------
__global__ __launch_bounds__(256) void k_proj(const _Float16* __restrict__ A,
                                              const _Float16* __restrict__ W,
                                              const float* __restrict__ bias,
                                              float* __restrict__ out) {
    int mt = blockIdx.x, ot = blockIdx.y;
    int tid = threadIdx.x, w = tid >> 6, lane = tid & 63;
    int lr = lane & 15, lg = lane >> 4;
    const _Float16* ap = A + (size_t)(mt * 64 + w * 16 + lr) * DM + lg * 8;
    const _Float16* wp = W + (size_t)(ot * 64 + lr) * DM + lg * 8;
    f32x4 zero = {0.f, 0.f, 0.f, 0.f};
    f32x4 acc[4] = {zero, zero, zero, zero};
    for (int ki = 0; ki < DM / 32; ++ki) {
        half8 af = *(const half8*)(ap + ki * 32);
#pragma unroll
        for (int ob = 0; ob < 4; ++ob) {
            half8 bf = *(const half8*)(wp + (size_t)(ob * 16) * DM + ki * 32);
            acc[ob] = __builtin_amdgcn_mfma_f32_16x16x32_f16(af, bf, acc[ob], 0, 0, 0);
        }
    }
#pragma unroll
    for (int ob = 0; ob < 4; ++ob) {
        int o = ot * 64 + ob * 16 + lr;
        float b = bias[o];
#pragma unroll
        for (int i = 0; i < 4; ++i) {
            int m = mt * 64 + w * 16 + lg * 4 + i;
            out[(size_t)m * DM + o] = acc[ob][i] + b;
        }
    }
}

// ---------------------------------------------------------------------------
extern "C" void kernel_launch(void* const* d_in, const int* in_sizes, int n_in,
                              void* d_out, int out_size, void* d_ws, size_t ws_size,
                              hipStream_t stream) {
    const float* Q = (const float*)d_in[0];
    const float* K = (const float*)d_in[1];
    const float* V = (const float*)d_in[2];
    const float* Wo = (const float*)d_in[3];
    const float* bo = (const float*)d_in[4];
    float* out = (float*)d_out;
    char* ws = (char*)d_ws;

    _Float16* Qh = (_Float16*)(ws);                     // 8 MB
    _Float16* Kh = (_Float16*)(ws + (8u << 20));        // 8 MB
    _Float16* Vt = (_Float16*)(ws + (16u << 20));       // 8 MB
    _Float16* Oatt = (_Float16*)(ws + (24u << 20));     // 8 MB
    _Float16* Wh = (_Float16*)(ws);                     // 2 MB, reuses Qh after attn

    const int n4 = N_B * S_LEN * DM / 4;                // 1,048,576
    k_regroup<<<n4 / 256, 256, 0, stream>>>(Q, Qh, n4);
    k_regroup<<<n4 / 256, 256, 0, stream>>>(K, Kh, n4);
    k_vt<<<dim3(S_LEN / 64, NH, N_B), 256, 0, stream>>>(V, Vt);
    k_attn<<<dim3(S_LEN / 64, N_B * NH), 256, 0, stream>>>(Qh, Kh, Vt, Oatt);
    k_cvt<<<(DM * DM / 4) / 256, 256, 0, stream>>>(Wo, Wh, DM * DM / 4);
    k_proj<<<dim3(N_B * S_LEN / 64, DM / 64), 256, 0, stream>>>(Oatt, Wh, bo, out);
}

// Round 3
// 221.237 us; speedup vs baseline: 1.5136x; 1.5136x over previous
//
#include <hip/hip_runtime.h>

typedef _Float16 half8 __attribute__((ext_vector_type(8)));
typedef _Float16 half4 __attribute__((ext_vector_type(4)));
typedef float f32x4 __attribute__((ext_vector_type(4)));

#define N_B 2
#define S_LEN 2048
#define NH 16
#define HD 64
#define DM 1024

__device__ __forceinline__ void gload16(const void* g, void* l) {
    __builtin_amdgcn_global_load_lds(
        (const __attribute__((address_space(1))) unsigned int*)g,
        (__attribute__((address_space(3))) unsigned int*)l, 16, 0, 0);
}

// ---------------------------------------------------------------------------
// Prep 1: convert f32 [n][s][h*64+d] -> f16 [n][h][s][d]   (K)
// ---------------------------------------------------------------------------
__global__ __launch_bounds__(256) void k_regroup(const float* __restrict__ in,
                                                 _Float16* __restrict__ out,
                                                 int n4) {
    int i = blockIdx.x * blockDim.x + threadIdx.x;
    if (i >= n4) return;
    float4 v = ((const float4*)in)[i];
    int base = i * 4;
    int d = base & 63;
    int h = (base >> 6) & 15;
    int s = (base >> 10) & 2047;
    int n = base >> 21;
    size_t o = ((size_t)((n * NH + h) * S_LEN + s)) * HD + d;
    half4 hv = {(_Float16)v.x, (_Float16)v.y, (_Float16)v.z, (_Float16)v.w};
    *(half4*)(out + o) = hv;
}

// ---------------------------------------------------------------------------
// Prep 2: V f32 [n][s][h*64+d] -> Vt f16 [n][h][d][s]  (LDS transpose, 64x64)
// ---------------------------------------------------------------------------
__global__ __launch_bounds__(256) void k_vt(const float* __restrict__ V,
                                            _Float16* __restrict__ Vt) {
    __shared__ _Float16 tile[64][65];
    int st = blockIdx.x, h = blockIdx.y, n = blockIdx.z;
    int c = threadIdx.x & 63, r0 = threadIdx.x >> 6;  // r0: 0..3
#pragma unroll
    for (int i = 0; i < 16; ++i) {
        int r = i * 4 + r0;
        tile[r][c] = (_Float16)V[((size_t)(n * S_LEN) + st * 64 + r) * DM + h * HD + c];
    }
    __syncthreads();
#pragma unroll
    for (int i = 0; i < 16; ++i) {
        int d = i * 4 + r0;
        Vt[((size_t)((n * NH + h) * HD + d)) * S_LEN + st * 64 + c] = tile[c][d];
    }
}

// ---------------------------------------------------------------------------
// Prep 3: flat f32 -> f16 convert (W_out, layout [o][i] kept)
// ---------------------------------------------------------------------------
__global__ __launch_bounds__(256) void k_cvt(const float* __restrict__ in,
                                             _Float16* __restrict__ out, int n4) {
    int i = blockIdx.x * blockDim.x + threadIdx.x;
    if (i >= n4) return;
    float4 v = ((const float4*)in)[i];
    half4 hv = {(_Float16)v.x, (_Float16)v.y, (_Float16)v.z, (_Float16)v.w};
    *(half4*)(out + (size_t)i * 4) = hv;
}

// ---------------------------------------------------------------------------
// Flash attention: grid (32 qtiles, 32 n*h), 256 thr = 4 waves x 16 q-rows.
// K/V tiles LDS-staged (shared by 4 waves), double-buffered via
// global_load_lds with counted vmcnt(4). XOR swizzle applied on the per-lane
// GLOBAL source address (LDS dest linear), undone on the ds_read side.
// Last iteration is peeled with NO stage + vmcnt(0): zero outstanding
// DMA-to-LDS at s_endpgm (late-landing DMA would corrupt a successor
// workgroup's LDS -> replay-dependent corruption).
// ---------------------------------------------------------------------------
__device__ __forceinline__ int swz(int b) { return b ^ (((b >> 7) & 7) << 4); }

__global__ __launch_bounds__(256) void k_attn(const float* __restrict__ Q,
                                              const _Float16* __restrict__ Kh,
                                              const _Float16* __restrict__ Vth,
                                              _Float16* __restrict__ Oatt) {
    __shared__ _Float16 KT[2][64 * 64];   // 16 KB
    __shared__ _Float16 VS[2][64 * 64];   // 16 KB
    __shared__ _Float16 PL[4][16 * 64];   // 8 KB (per-wave private)

    const int nh = blockIdx.y;     // n*16 + h
    const int qt = blockIdx.x;     // q tile of 64
    const int tid = threadIdx.x;
    const int w = tid >> 6;
    const int lane = tid & 63;
    const int lr = lane & 15;
    const int lg = lane >> 4;
    const int n = nh >> 4, h = nh & 15;

    const size_t head = (size_t)nh * S_LEN * HD;
    const char* Khead = (const char*)(Kh + head);
    const char* Vhead = (const char*)(Vth + head);

    // ---- Q load fused from original f32 layout ----
    const float* qrow = Q + ((size_t)(n * S_LEN) + qt * 64 + w * 16 + lr) * DM + h * HD + lg * 8;
    float4 qa = *(const float4*)(qrow);
    float4 qb = *(const float4*)(qrow + 4);
    float4 qc = *(const float4*)(qrow + 32);
    float4 qd = *(const float4*)(qrow + 36);
    half8 qf0 = {(_Float16)qa.x, (_Float16)qa.y, (_Float16)qa.z, (_Float16)qa.w,
                 (_Float16)qb.x, (_Float16)qb.y, (_Float16)qb.z, (_Float16)qb.w};
    half8 qf1 = {(_Float16)qc.x, (_Float16)qc.y, (_Float16)qc.z, (_Float16)qc.w,
                 (_Float16)qd.x, (_Float16)qd.y, (_Float16)qd.z, (_Float16)qd.w};

    f32x4 zero = {0.f, 0.f, 0.f, 0.f};
    f32x4 oacc[4] = {zero, zero, zero, zero};
    float m_i[4], l_i[4];
#pragma unroll
    for (int i = 0; i < 4; ++i) { m_i[i] = -1e30f; l_i[i] = 0.f; }

    char* pl = (char*)&PL[w][0];

    // staging geometry: wave w stages 2 x 1KB regions of each 8KB tile.
    const int rr = lane >> 3;          // row-within-8  (== row & 7)
    const int cb = (lane & 7) * 16;    // 16B column block
    const int gcb = cb ^ (rr << 4);    // inverse-swizzled global column

    auto STAGE = [&](int kt, int b) {
#pragma unroll
        for (int j = 0; j < 2; ++j) {
            int row = (w * 2 + j) * 8 + rr;
            gload16(Khead + ((size_t)(kt * 64 + row)) * 128 + gcb,
                    (char*)&KT[b][0] + (w * 2 + j) * 1024);
            gload16(Vhead + (size_t)row * 4096 + (size_t)kt * 128 + gcb,
                    (char*)&VS[b][0] + (w * 2 + j) * 1024);
        }
    };

    auto BODY = [&](int kt, int bc, int bs, bool do_stage, bool do_end_barrier) {
        if (do_stage) {
            STAGE(kt + 1, bs);
            asm volatile("s_waitcnt vmcnt(4)" ::: "memory");
        } else {
            asm volatile("s_waitcnt vmcnt(0)" ::: "memory");
        }
        __builtin_amdgcn_s_barrier();

        const char* ldsK = (const char*)&KT[bc][0];
        const char* ldsV = (const char*)&VS[bc][0];

        // ---- S = Q K^T ----
        f32x4 s[4] = {zero, zero, zero, zero};
#pragma unroll
        for (int nb = 0; nb < 4; ++nb) {
            int row = nb * 16 + lr;
            int sw = (row & 7) << 4;
            const char* kp = ldsK + row * 128;
            half8 kf0 = *(const half8*)(kp + ((lg * 16) ^ sw));
            half8 kf1 = *(const half8*)(kp + ((64 + lg * 16) ^ sw));
            s[nb] = __builtin_amdgcn_mfma_f32_16x16x32_f16(qf0, kf0, s[nb], 0, 0, 0);
            s[nb] = __builtin_amdgcn_mfma_f32_16x16x32_f16(qf1, kf1, s[nb], 0, 0, 0);
        }
        // ---- online softmax ----
#pragma unroll
        for (int i = 0; i < 4; ++i) {
            float rm = fmaxf(fmaxf(s[0][i], s[1][i]), fmaxf(s[2][i], s[3][i]));
#pragma unroll
            for (int o = 1; o < 16; o <<= 1) rm = fmaxf(rm, __shfl_xor(rm, o));
            float mn = fmaxf(m_i[i], rm);
            float sc = __expf(m_i[i] - mn);
            m_i[i] = mn;
            float rs = 0.f;
#pragma unroll
            for (int nb = 0; nb < 4; ++nb) {
                float p = __expf(s[nb][i] - mn);
                s[nb][i] = p;
                rs += p;
            }
#pragma unroll
            for (int o = 1; o < 16; o <<= 1) rs += __shfl_xor(rs, o);
            l_i[i] = l_i[i] * sc + rs;
#pragma unroll
            for (int ob = 0; ob < 4; ++ob) oacc[ob][i] *= sc;
        }
        // ---- P -> LDS (f16, per-wave private, XOR swizzle) ----
#pragma unroll
        for (int nb = 0; nb < 4; ++nb)
#pragma unroll
            for (int i = 0; i < 4; ++i)
                *(_Float16*)(pl + swz((lg * 4 + i) * 128 + (nb * 16 + lr) * 2)) =
                    (_Float16)s[nb][i];
        half8 pa0 = *(const half8*)(pl + swz(lr * 128 + lg * 16));
        half8 pa1 = *(const half8*)(pl + swz(lr * 128 + 64 + lg * 16));
        // ---- O += P V ----
#pragma unroll
        for (int ob = 0; ob < 4; ++ob) {
            int row = ob * 16 + lr;
            int sw = (row & 7) << 4;
            const char* vp = ldsV + row * 128;
            half8 vf0 = *(const half8*)(vp + ((lg * 16) ^ sw));
            half8 vf1 = *(const half8*)(vp + ((64 + lg * 16) ^ sw));
            oacc[ob] = __builtin_amdgcn_mfma_f32_16x16x32_f16(pa0, vf0, oacc[ob], 0, 0, 0);
            oacc[ob] = __builtin_amdgcn_mfma_f32_16x16x32_f16(pa1, vf1, oacc[ob], 0, 0, 0);
        }
        if (do_end_barrier) __builtin_amdgcn_s_barrier();
    };

    STAGE(0, 0);
    for (int t = 0; t < 15; ++t) {
        BODY(2 * t, 0, 1, true, true);
        BODY(2 * t + 1, 1, 0, true, true);
    }
    BODY(30, 0, 1, true, true);
    BODY(31, 1, 0, false, false);   // peeled: no stage, vmcnt(0), no DMA at endpgm

    // ---- epilogue: Oatt[n][q][h*64+d] = oacc / l ----
#pragma unroll
    for (int i = 0; i < 4; ++i) {
        float inv = 1.f / l_i[i];
        int q = qt * 64 + w * 16 + lg * 4 + i;
#pragma unroll
        for (int ob = 0; ob < 4; ++ob) {
            int d = ob * 16 + lr;
            Oatt[((size_t)(n * S_LEN + q)) * DM + h * HD + d] = (_Float16)(oacc[ob][i] * inv);
        }
    }
}

// ---------------------------------------------------------------------------
// Projection: out[m][o] = sum_i A[m][i] * W[o][i] + b[o]   (M=4096,O=1024,K=1024)
// ---------------------------------------------------------------------------
__global__ __launch_bounds__(256) void k_proj(const _Float16* __restrict__ A,
                                              const _Float16* __restrict__ W,
                                              const float* __restrict__ bias,
                                              float* __restrict__ out) {
    int mt = blockIdx.x, ot = blockIdx.y;
    int tid = threadIdx.x, w = tid >> 6, lane = tid & 63;
    int lr = lane & 15, lg = lane >> 4;
    const _Float16* ap = A + (size_t)(mt * 64 + w * 16 + lr) * DM + lg * 8;
    const _Float16* wp = W + (size_t)(ot * 64 + lr) * DM + lg * 8;
    f32x4 zero = {0.f, 0.f, 0.f, 0.f};
    f32x4 acc[4] = {zero, zero, zero, zero};
    for (int ki = 0; ki < DM / 32; ++ki) {
        half8 af = *(const half8*)(ap + ki * 32);
#pragma unroll
        for (int ob = 0; ob < 4; ++ob) {
            half8 bf = *(const half8*)(wp + (size_t)(ob * 16) * DM + ki * 32);
            acc[ob] = __builtin_amdgcn_mfma_f32_16x16x32_f16(af, bf, acc[ob], 0, 0, 0);
        }
    }
#pragma unroll
    for (int ob = 0; ob < 4; ++ob) {
        int o = ot * 64 + ob * 16 + lr;
        float b = bias[o];
#pragma unroll
        for (int i = 0; i < 4; ++i) {
            int m = mt * 64 + w * 16 + lg * 4 + i;
            out[(size_t)m * DM + o] = acc[ob][i] + b;
        }
    }
}

// ---------------------------------------------------------------------------
extern "C" void kernel_launch(void* const* d_in, const int* in_sizes, int n_in,
                              void* d_out, int out_size, void* d_ws, size_t ws_size,
                              hipStream_t stream) {
    const float* Q = (const float*)d_in[0];
    const float* K = (const float*)d_in[1];
    const float* V = (const float*)d_in[2];
    const float* Wo = (const float*)d_in[3];
    const float* bo = (const float*)d_in[4];
    float* out = (float*)d_out;
    char* ws = (char*)d_ws;

    _Float16* Kh = (_Float16*)(ws);                     // 8 MB
    _Float16* Vt = (_Float16*)(ws + (8u << 20));        // 8 MB
    _Float16* Oatt = (_Float16*)(ws + (16u << 20));     // 8 MB
    _Float16* Wh = (_Float16*)(ws + (24u << 20));       // 2 MB

    const int n4 = N_B * S_LEN * DM / 4;                // 1,048,576
    k_regroup<<<n4 / 256, 256, 0, stream>>>(K, Kh, n4);
    k_vt<<<dim3(S_LEN / 64, NH, N_B), 256, 0, stream>>>(V, Vt);
    k_cvt<<<(DM * DM / 4) / 256, 256, 0, stream>>>(Wo, Wh, DM * DM / 4);
    k_attn<<<dim3(S_LEN / 64, N_B * NH), 256, 0, stream>>>(Q, Kh, Vt, Oatt);
    k_proj<<<dim3(N_B * S_LEN / 64, DM / 64), 256, 0, stream>>>(Oatt, Wh, bo, out);
}

// Round 5
// 165.593 us; speedup vs baseline: 2.0222x; 1.3360x over previous
//
#include <hip/hip_runtime.h>

typedef _Float16 half8 __attribute__((ext_vector_type(8)));
typedef _Float16 half4 __attribute__((ext_vector_type(4)));
typedef float f32x4 __attribute__((ext_vector_type(4)));

#define N_B 2
#define S_LEN 2048
#define NH 16
#define HD 64
#define DM 1024

__device__ __forceinline__ void gload16(const void* g, void* l) {
    __builtin_amdgcn_global_load_lds(
        (const __attribute__((address_space(1))) unsigned int*)g,
        (__attribute__((address_space(3))) unsigned int*)l, 16, 0, 0);
}

// ---------------------------------------------------------------------------
// Prep 1: convert f32 [n][s][h*64+d] -> f16 [n][h][s][d]   (K)
// ---------------------------------------------------------------------------
__global__ __launch_bounds__(256) void k_regroup(const float* __restrict__ in,
                                                 _Float16* __restrict__ out,
                                                 int n4) {
    int i = blockIdx.x * blockDim.x + threadIdx.x;
    if (i >= n4) return;
    float4 v = ((const float4*)in)[i];
    int base = i * 4;
    int d = base & 63;
    int h = (base >> 6) & 15;
    int s = (base >> 10) & 2047;
    int n = base >> 21;
    size_t o = ((size_t)((n * NH + h) * S_LEN + s)) * HD + d;
    half4 hv = {(_Float16)v.x, (_Float16)v.y, (_Float16)v.z, (_Float16)v.w};
    *(half4*)(out + o) = hv;
}

// ---------------------------------------------------------------------------
// Prep 2: V f32 [n][s][h*64+d] -> Vt f16 [n][h][d][s]  (LDS transpose, 64x64)
// ---------------------------------------------------------------------------
__global__ __launch_bounds__(256) void k_vt(const float* __restrict__ V,
                                            _Float16* __restrict__ Vt) {
    __shared__ _Float16 tile[64][65];
    int st = blockIdx.x, h = blockIdx.y, n = blockIdx.z;
    int c = threadIdx.x & 63, r0 = threadIdx.x >> 6;  // r0: 0..3
#pragma unroll
    for (int i = 0; i < 16; ++i) {
        int r = i * 4 + r0;
        tile[r][c] = (_Float16)V[((size_t)(n * S_LEN) + st * 64 + r) * DM + h * HD + c];
    }
    __syncthreads();
#pragma unroll
    for (int i = 0; i < 16; ++i) {
        int d = i * 4 + r0;
        Vt[((size_t)((n * NH + h) * HD + d)) * S_LEN + st * 64 + c] = tile[c][d];
    }
}

// ---------------------------------------------------------------------------
// Prep 3: flat f32 -> f16 convert (W_out, layout [o][i] kept)
// ---------------------------------------------------------------------------
__global__ __launch_bounds__(256) void k_cvt(const float* __restrict__ in,
                                             _Float16* __restrict__ out, int n4) {
    int i = blockIdx.x * blockDim.x + threadIdx.x;
    if (i >= n4) return;
    float4 v = ((const float4*)in)[i];
    half4 hv = {(_Float16)v.x, (_Float16)v.y, (_Float16)v.z, (_Float16)v.w};
    *(half4*)(out + (size_t)i * 4) = hv;
}

// ---------------------------------------------------------------------------
// Flash attention, SWAPPED QK^T (lane-local softmax), conservative 2-phase
// sync: per tile { STAGE(next -> buf^1); compute(buf); __syncthreads(); }.
// __syncthreads() emits s_waitcnt vmcnt(0) lgkmcnt(0) + s_barrier, so every
// DMA/LDS op is drained at each tile boundary (no hand vmcnt arithmetic, no
// raw s_barrier scheduling hazards). Stage overlaps the full compute phase.
// Last tile stages nothing -> zero outstanding DMA at s_endpgm.
// ---------------------------------------------------------------------------
__global__ __launch_bounds__(256) void k_attn(const float* __restrict__ Q,
                                              const _Float16* __restrict__ Kh,
                                              const _Float16* __restrict__ Vth,
                                              _Float16* __restrict__ Oatt) {
    __shared__ _Float16 KT[2][64 * 64];   // 16 KB
    __shared__ _Float16 VS[2][64 * 64];   // 16 KB
    __shared__ _Float16 PL[4][16 * 64];   // 8 KB (per-wave private)

    const int nh = blockIdx.y;     // n*16 + h
    const int qt = blockIdx.x;     // q tile of 64
    const int tid = threadIdx.x;
    const int w = tid >> 6;
    const int lane = tid & 63;
    const int lr = lane & 15;
    const int lg = lane >> 4;
    const int lg4 = lg * 4;
    const int n = nh >> 4, h = nh & 15;

    const size_t head = (size_t)nh * S_LEN * HD;
    const char* Khead = (const char*)(Kh + head);
    const char* Vhead = (const char*)(Vth + head);

    // ---- Q load fused from original f32 layout (B-fragment: q=lr, k=8lg+j)
    const float* qrow = Q + ((size_t)(n * S_LEN) + qt * 64 + w * 16 + lr) * DM + h * HD + lg * 8;
    float4 qa = *(const float4*)(qrow);
    float4 qb = *(const float4*)(qrow + 4);
    float4 qc = *(const float4*)(qrow + 32);
    float4 qd = *(const float4*)(qrow + 36);
    half8 qf0 = {(_Float16)qa.x, (_Float16)qa.y, (_Float16)qa.z, (_Float16)qa.w,
                 (_Float16)qb.x, (_Float16)qb.y, (_Float16)qb.z, (_Float16)qb.w};
    half8 qf1 = {(_Float16)qc.x, (_Float16)qc.y, (_Float16)qc.z, (_Float16)qc.w,
                 (_Float16)qd.x, (_Float16)qd.y, (_Float16)qd.z, (_Float16)qd.w};

    f32x4 zero = {0.f, 0.f, 0.f, 0.f};
    f32x4 oacc[4] = {zero, zero, zero, zero};
    float m_q = -1e30f, l_q = 0.f;   // softmax state for query lr (4x redundant over lg)

    char* pl = (char*)&PL[w][0];
    const int pmask = (lr & 7) << 4;
    // loop-invariant P write/read addresses (row = query lr, stride 128B)
    int pw0 = lr * 128 + ((0 * 32 + lg * 8) ^ pmask);
    int pw1 = lr * 128 + ((1 * 32 + lg * 8) ^ pmask);
    int pw2 = lr * 128 + ((2 * 32 + lg * 8) ^ pmask);
    int pw3 = lr * 128 + ((3 * 32 + lg * 8) ^ pmask);
    int pr0 = lr * 128 + ((lg * 16) ^ pmask);
    int pr1 = lr * 128 + ((64 + lg * 16) ^ pmask);

    // staging geometry: wave w stages 2 x 1KB regions of each 8KB tile.
    const int rr = lane >> 3;          // row-within-8
    const int cb = (lane & 7) * 16;    // 16B column block
    const int gcb = cb ^ (rr << 4);    // inverse-swizzled global column

    auto STAGE = [&](int kt, int b) {
#pragma unroll
        for (int j = 0; j < 2; ++j) {
            int row = (w * 2 + j) * 8 + rr;
            gload16(Khead + ((size_t)(kt * 64 + row)) * 128 + gcb,
                    (char*)&KT[b][0] + (w * 2 + j) * 1024);
            gload16(Vhead + (size_t)row * 4096 + (size_t)kt * 128 + gcb,
                    (char*)&VS[b][0] + (w * 2 + j) * 1024);
        }
    };

    auto BODY = [&](int kt, int buf, bool do_stage) {
        if (do_stage) STAGE(kt + 1, buf ^ 1);

        const char* ldsK = (const char*)&KT[buf][0];
        const char* ldsV = (const char*)&VS[buf][0];

        // ---- S^T = K Q^T : lane holds scores for query lr, keys 16nb+4lg+r
        f32x4 st[4] = {zero, zero, zero, zero};
#pragma unroll
        for (int nb = 0; nb < 4; ++nb) {
            int row = nb * 16 + lr;
            int sw = (row & 7) << 4;
            const char* kp = ldsK + row * 128;
            half8 kf0 = *(const half8*)(kp + ((lg * 16) ^ sw));
            half8 kf1 = *(const half8*)(kp + ((64 + lg * 16) ^ sw));
            st[nb] = __builtin_amdgcn_mfma_f32_16x16x32_f16(kf0, qf0, st[nb], 0, 0, 0);
            st[nb] = __builtin_amdgcn_mfma_f32_16x16x32_f16(kf1, qf1, st[nb], 0, 0, 0);
        }
        // ---- lane-local online softmax for query lr ----
        float t0 = fmaxf(fmaxf(st[0][0], st[0][1]), fmaxf(st[0][2], st[0][3]));
        float t1 = fmaxf(fmaxf(st[1][0], st[1][1]), fmaxf(st[1][2], st[1][3]));
        float t2 = fmaxf(fmaxf(st[2][0], st[2][1]), fmaxf(st[2][2], st[2][3]));
        float t3 = fmaxf(fmaxf(st[3][0], st[3][1]), fmaxf(st[3][2], st[3][3]));
        float tm = fmaxf(fmaxf(t0, t1), fmaxf(t2, t3));
        tm = fmaxf(tm, __shfl_xor(tm, 16));
        tm = fmaxf(tm, __shfl_xor(tm, 32));
        float mn = fmaxf(m_q, tm);
        float sc = __expf(m_q - mn);
        m_q = mn;
        float rs = 0.f;
#pragma unroll
        for (int nb = 0; nb < 4; ++nb)
#pragma unroll
            for (int r = 0; r < 4; ++r) {
                float p = __expf(st[nb][r] - mn);
                st[nb][r] = p;
                rs += p;
            }
        rs += __shfl_xor(rs, 16);
        rs += __shfl_xor(rs, 32);
        l_q = l_q * sc + rs;
        // ---- rescale O by sc of the queries this lane accumulates (q=4lg+r)
        float s0 = __shfl(sc, lg4 + 0);
        float s1 = __shfl(sc, lg4 + 1);
        float s2 = __shfl(sc, lg4 + 2);
        float s3 = __shfl(sc, lg4 + 3);
#pragma unroll
        for (int ob = 0; ob < 4; ++ob) {
            oacc[ob][0] *= s0; oacc[ob][1] *= s1;
            oacc[ob][2] *= s2; oacc[ob][3] *= s3;
        }
        // ---- P -> LDS: 4 x b64, row q=lr, k=16nb+4lg+{0..3}, XOR swizzled
        half4 p0 = {(_Float16)st[0][0], (_Float16)st[0][1], (_Float16)st[0][2], (_Float16)st[0][3]};
        half4 p1 = {(_Float16)st[1][0], (_Float16)st[1][1], (_Float16)st[1][2], (_Float16)st[1][3]};
        half4 p2 = {(_Float16)st[2][0], (_Float16)st[2][1], (_Float16)st[2][2], (_Float16)st[2][3]};
        half4 p3 = {(_Float16)st[3][0], (_Float16)st[3][1], (_Float16)st[3][2], (_Float16)st[3][3]};
        *(half4*)(pl + pw0) = p0;
        *(half4*)(pl + pw1) = p1;
        *(half4*)(pl + pw2) = p2;
        *(half4*)(pl + pw3) = p3;
        half8 pa0 = *(const half8*)(pl + pr0);
        half8 pa1 = *(const half8*)(pl + pr1);
        // ---- O += P V ----
#pragma unroll
        for (int ob = 0; ob < 4; ++ob) {
            int row = ob * 16 + lr;
            int sw = (row & 7) << 4;
            const char* vp = ldsV + row * 128;
            half8 vf0 = *(const half8*)(vp + ((lg * 16) ^ sw));
            half8 vf1 = *(const half8*)(vp + ((64 + lg * 16) ^ sw));
            oacc[ob] = __builtin_amdgcn_mfma_f32_16x16x32_f16(pa0, vf0, oacc[ob], 0, 0, 0);
            oacc[ob] = __builtin_amdgcn_mfma_f32_16x16x32_f16(pa1, vf1, oacc[ob], 0, 0, 0);
        }
        if (do_stage) __syncthreads();   // full drain (vmcnt 0 + lgkmcnt 0) + barrier
    };

    STAGE(0, 0);
    __syncthreads();
    for (int t = 0; t < 31; ++t) BODY(t, t & 1, true);
    BODY(31, 1, false);   // no stage, no trailing barrier, no DMA at endpgm

    // ---- epilogue: Oatt[n][q][h*64+d] = oacc / l  (l for q=4lg+r via shfl)
    float li0 = __shfl(l_q, lg4 + 0);
    float li1 = __shfl(l_q, lg4 + 1);
    float li2 = __shfl(l_q, lg4 + 2);
    float li3 = __shfl(l_q, lg4 + 3);
    float inv[4] = {1.f / li0, 1.f / li1, 1.f / li2, 1.f / li3};
#pragma unroll
    for (int i = 0; i < 4; ++i) {
        int q = qt * 64 + w * 16 + lg4 + i;
#pragma unroll
        for (int ob = 0; ob < 4; ++ob) {
            int d = ob * 16 + lr;
            Oatt[((size_t)(n * S_LEN + q)) * DM + h * HD + d] = (_Float16)(oacc[ob][i] * inv[i]);
        }
    }
}

// ---------------------------------------------------------------------------
// Projection: out[m][o] = sum_i A[m][i] * W[o][i] + b[o]   (M=4096,O=1024,K=1024)
// ---------------------------------------------------------------------------
__global__ __launch_bounds__(256) void k_proj(const _Float16* __restrict__ A,
                                              const _Float16* __restrict__ W,
                                              const float* __restrict__ bias,
                                              float* __restrict__ out) {
    int mt = blockIdx.x, ot = blockIdx.y;
    int tid = threadIdx.x, w = tid >> 6, lane = tid & 63;
    int lr = lane & 15, lg = lane >> 4;
    const _Float16* ap = A + (size_t)(mt * 64 + w * 16 + lr) * DM + lg * 8;
    const _Float16* wp = W + (size_t)(ot * 64 + lr) * DM + lg * 8;
    f32x4 zero = {0.f, 0.f, 0.f, 0.f};
    f32x4 acc[4] = {zero, zero, zero, zero};
    for (int ki = 0; ki < DM / 32; ++ki) {
        half8 af = *(const half8*)(ap + ki * 32);
#pragma unroll
        for (int ob = 0; ob < 4; ++ob) {
            half8 bf = *(const half8*)(wp + (size_t)(ob * 16) * DM + ki * 32);
            acc[ob] = __builtin_amdgcn_mfma_f32_16x16x32_f16(af, bf, acc[ob], 0, 0, 0);
        }
    }
#pragma unroll
    for (int ob = 0; ob < 4; ++ob) {
        int o = ot * 64 + ob * 16 + lr;
        float b = bias[o];
#pragma unroll
        for (int i = 0; i < 4; ++i) {
            int m = mt * 64 + w * 16 + lg * 4 + i;
            out[(size_t)m * DM + o] = acc[ob][i] + b;
        }
    }
}

// ---------------------------------------------------------------------------
extern "C" void kernel_launch(void* const* d_in, const int* in_sizes, int n_in,
                              void* d_out, int out_size, void* d_ws, size_t ws_size,
                              hipStream_t stream) {
    const float* Q = (const float*)d_in[0];
    const float* K = (const float*)d_in[1];
    const float* V = (const float*)d_in[2];
    const float* Wo = (const float*)d_in[3];
    const float* bo = (const float*)d_in[4];
    float* out = (float*)d_out;
    char* ws = (char*)d_ws;

    _Float16* Kh = (_Float16*)(ws);                     // 8 MB
    _Float16* Vt = (_Float16*)(ws + (8u << 20));        // 8 MB
    _Float16* Oatt = (_Float16*)(ws + (16u << 20));     // 8 MB
    _Float16* Wh = (_Float16*)(ws + (24u << 20));       // 2 MB

    const int n4 = N_B * S_LEN * DM / 4;                // 1,048,576
    k_regroup<<<n4 / 256, 256, 0, stream>>>(K, Kh, n4);
    k_vt<<<dim3(S_LEN / 64, NH, N_B), 256, 0, stream>>>(V, Vt);
    k_cvt<<<(DM * DM / 4) / 256, 256, 0, stream>>>(Wo, Wh, DM * DM / 4);
    k_attn<<<dim3(S_LEN / 64, N_B * NH), 256, 0, stream>>>(Q, Kh, Vt, Oatt);
    k_proj<<<dim3(N_B * S_LEN / 64, DM / 64), 256, 0, stream>>>(Oatt, Wh, bo, out);
}

// Round 6
// 162.205 us; speedup vs baseline: 2.0645x; 1.0209x over previous
//
#include <hip/hip_runtime.h>

typedef _Float16 half8 __attribute__((ext_vector_type(8)));
typedef _Float16 half4 __attribute__((ext_vector_type(4)));
typedef float f32x4 __attribute__((ext_vector_type(4)));

#define N_B 2
#define S_LEN 2048
#define NH 16
#define HD 64
#define DM 1024
#define LOG2E 1.44269504088896f

__device__ __forceinline__ void gload16(const void* g, void* l) {
    __builtin_amdgcn_global_load_lds(
        (const __attribute__((address_space(1))) unsigned int*)g,
        (__attribute__((address_space(3))) unsigned int*)l, 16, 0, 0);
}

__device__ __forceinline__ float fexp2(float x) {
    float r;
    asm("v_exp_f32 %0, %1" : "=v"(r) : "v"(x));
    return r;
}

// ---------------------------------------------------------------------------
// Prep 1: convert f32 [n][s][h*64+d] -> f16 [n][h][s][d]   (K)
// ---------------------------------------------------------------------------
__global__ __launch_bounds__(256) void k_regroup(const float* __restrict__ in,
                                                 _Float16* __restrict__ out,
                                                 int n4) {
    int i = blockIdx.x * blockDim.x + threadIdx.x;
    if (i >= n4) return;
    float4 v = ((const float4*)in)[i];
    int base = i * 4;
    int d = base & 63;
    int h = (base >> 6) & 15;
    int s = (base >> 10) & 2047;
    int n = base >> 21;
    size_t o = ((size_t)((n * NH + h) * S_LEN + s)) * HD + d;
    half4 hv = {(_Float16)v.x, (_Float16)v.y, (_Float16)v.z, (_Float16)v.w};
    *(half4*)(out + o) = hv;
}

// ---------------------------------------------------------------------------
// Prep 2: V f32 [n][s][h*64+d] -> Vt f16 [n][h][d][s]  (LDS transpose, 64x64)
// ---------------------------------------------------------------------------
__global__ __launch_bounds__(256) void k_vt(const float* __restrict__ V,
                                            _Float16* __restrict__ Vt) {
    __shared__ _Float16 tile[64][65];
    int st = blockIdx.x, h = blockIdx.y, n = blockIdx.z;
    int c = threadIdx.x & 63, r0 = threadIdx.x >> 6;  // r0: 0..3
#pragma unroll
    for (int i = 0; i < 16; ++i) {
        int r = i * 4 + r0;
        tile[r][c] = (_Float16)V[((size_t)(n * S_LEN) + st * 64 + r) * DM + h * HD + c];
    }
    __syncthreads();
#pragma unroll
    for (int i = 0; i < 16; ++i) {
        int d = i * 4 + r0;
        Vt[((size_t)((n * NH + h) * HD + d)) * S_LEN + st * 64 + c] = tile[c][d];
    }
}

// ---------------------------------------------------------------------------
// Prep 3: flat f32 -> f16 convert (W_out, layout [o][i] kept)
// ---------------------------------------------------------------------------
__global__ __launch_bounds__(256) void k_cvt(const float* __restrict__ in,
                                             _Float16* __restrict__ out, int n4) {
    int i = blockIdx.x * blockDim.x + threadIdx.x;
    if (i >= n4) return;
    float4 v = ((const float4*)in)[i];
    half4 hv = {(_Float16)v.x, (_Float16)v.y, (_Float16)v.z, (_Float16)v.w};
    *(half4*)(out + (size_t)i * 4) = hv;
}

// ---------------------------------------------------------------------------
// Flash attention, SWAPPED QK^T (lane-local softmax), 2-phase __syncthreads
// pipeline. XCD-aware block swizzle: all 32 qt-blocks of nh values
// {x, x+8, x+16, x+24} land on XCD x (id%8==x), making the K/V working set
// 2 MB per XCD -> L2-resident -> DMA latency hideable under compute.
// Softmax in exp2 domain: Q pre-scaled by log2(e); raw v_exp_f32.
// ---------------------------------------------------------------------------
__global__ __launch_bounds__(256) void k_attn(const float* __restrict__ Q,
                                              const _Float16* __restrict__ Kh,
                                              const _Float16* __restrict__ Vth,
                                              _Float16* __restrict__ Oatt) {
    __shared__ _Float16 KT[2][64 * 64];   // 16 KB
    __shared__ _Float16 VS[2][64 * 64];   // 16 KB
    __shared__ _Float16 PL[4][16 * 64];   // 8 KB (per-wave private)

    // XCD swizzle (bijective on 1024 = 8 * 128)
    const int id = blockIdx.x;
    const int xcd = id & 7;
    const int sl = id >> 3;            // 0..127
    const int nh = xcd + 8 * (sl >> 5);  // n*16 + h
    const int qt = sl & 31;              // q tile of 64

    const int tid = threadIdx.x;
    const int w = tid >> 6;
    const int lane = tid & 63;
    const int lr = lane & 15;
    const int lg = lane >> 4;
    const int lg4 = lg * 4;
    const int n = nh >> 4, h = nh & 15;

    const size_t head = (size_t)nh * S_LEN * HD;
    const char* Khead = (const char*)(Kh + head);
    const char* Vhead = (const char*)(Vth + head);

    // ---- Q load fused from original f32 layout, scaled by log2(e)
    const float* qrow = Q + ((size_t)(n * S_LEN) + qt * 64 + w * 16 + lr) * DM + h * HD + lg * 8;
    float4 qa = *(const float4*)(qrow);
    float4 qb = *(const float4*)(qrow + 4);
    float4 qc = *(const float4*)(qrow + 32);
    float4 qd = *(const float4*)(qrow + 36);
    half8 qf0 = {(_Float16)(qa.x * LOG2E), (_Float16)(qa.y * LOG2E),
                 (_Float16)(qa.z * LOG2E), (_Float16)(qa.w * LOG2E),
                 (_Float16)(qb.x * LOG2E), (_Float16)(qb.y * LOG2E),
                 (_Float16)(qb.z * LOG2E), (_Float16)(qb.w * LOG2E)};
    half8 qf1 = {(_Float16)(qc.x * LOG2E), (_Float16)(qc.y * LOG2E),
                 (_Float16)(qc.z * LOG2E), (_Float16)(qc.w * LOG2E),
                 (_Float16)(qd.x * LOG2E), (_Float16)(qd.y * LOG2E),
                 (_Float16)(qd.z * LOG2E), (_Float16)(qd.w * LOG2E)};

    f32x4 zero = {0.f, 0.f, 0.f, 0.f};
    f32x4 oacc[4] = {zero, zero, zero, zero};
    float m_q = -1e30f, l_q = 0.f;   // softmax state (exp2 domain) for query lr

    char* pl = (char*)&PL[w][0];
    const int pmask = (lr & 7) << 4;
    int pw0 = lr * 128 + ((0 * 32 + lg * 8) ^ pmask);
    int pw1 = lr * 128 + ((1 * 32 + lg * 8) ^ pmask);
    int pw2 = lr * 128 + ((2 * 32 + lg * 8) ^ pmask);
    int pw3 = lr * 128 + ((3 * 32 + lg * 8) ^ pmask);
    int pr0 = lr * 128 + ((lg * 16) ^ pmask);
    int pr1 = lr * 128 + ((64 + lg * 16) ^ pmask);

    // staging geometry: wave w stages 2 x 1KB regions of each 8KB tile.
    const int rr = lane >> 3;          // row-within-8
    const int cb = (lane & 7) * 16;    // 16B column block
    const int gcb = cb ^ (rr << 4);    // inverse-swizzled global column

    auto STAGE = [&](int kt, int b) {
#pragma unroll
        for (int j = 0; j < 2; ++j) {
            int row = (w * 2 + j) * 8 + rr;
            gload16(Khead + ((size_t)(kt * 64 + row)) * 128 + gcb,
                    (char*)&KT[b][0] + (w * 2 + j) * 1024);
            gload16(Vhead + (size_t)row * 4096 + (size_t)kt * 128 + gcb,
                    (char*)&VS[b][0] + (w * 2 + j) * 1024);
        }
    };

    auto BODY = [&](int kt, int buf, bool do_stage) {
        if (do_stage) STAGE(kt + 1, buf ^ 1);

        const char* ldsK = (const char*)&KT[buf][0];
        const char* ldsV = (const char*)&VS[buf][0];

        // ---- S^T = K Q^T : lane holds scores for query lr, keys 16nb+4lg+r
        f32x4 st[4] = {zero, zero, zero, zero};
#pragma unroll
        for (int nb = 0; nb < 4; ++nb) {
            int row = nb * 16 + lr;
            int sw = (row & 7) << 4;
            const char* kp = ldsK + row * 128;
            half8 kf0 = *(const half8*)(kp + ((lg * 16) ^ sw));
            half8 kf1 = *(const half8*)(kp + ((64 + lg * 16) ^ sw));
            st[nb] = __builtin_amdgcn_mfma_f32_16x16x32_f16(kf0, qf0, st[nb], 0, 0, 0);
            st[nb] = __builtin_amdgcn_mfma_f32_16x16x32_f16(kf1, qf1, st[nb], 0, 0, 0);
        }
        // ---- lane-local online softmax (exp2 domain) ----
        float t0 = fmaxf(fmaxf(st[0][0], st[0][1]), fmaxf(st[0][2], st[0][3]));
        float t1 = fmaxf(fmaxf(st[1][0], st[1][1]), fmaxf(st[1][2], st[1][3]));
        float t2 = fmaxf(fmaxf(st[2][0], st[2][1]), fmaxf(st[2][2], st[2][3]));
        float t3 = fmaxf(fmaxf(st[3][0], st[3][1]), fmaxf(st[3][2], st[3][3]));
        float tm = fmaxf(fmaxf(t0, t1), fmaxf(t2, t3));
        tm = fmaxf(tm, __shfl_xor(tm, 16));
        tm = fmaxf(tm, __shfl_xor(tm, 32));
        float mn = fmaxf(m_q, tm);
        float sc = fexp2(m_q - mn);
        m_q = mn;
        float rs = 0.f;
#pragma unroll
        for (int nb = 0; nb < 4; ++nb)
#pragma unroll
            for (int r = 0; r < 4; ++r) {
                float p = fexp2(st[nb][r] - mn);
                st[nb][r] = p;
                rs += p;
            }
        rs += __shfl_xor(rs, 16);
        rs += __shfl_xor(rs, 32);
        l_q = l_q * sc + rs;
        // ---- rescale O by sc of the queries this lane accumulates (q=4lg+r)
        float s0 = __shfl(sc, lg4 + 0);
        float s1 = __shfl(sc, lg4 + 1);
        float s2 = __shfl(sc, lg4 + 2);
        float s3 = __shfl(sc, lg4 + 3);
#pragma unroll
        for (int ob = 0; ob < 4; ++ob) {
            oacc[ob][0] *= s0; oacc[ob][1] *= s1;
            oacc[ob][2] *= s2; oacc[ob][3] *= s3;
        }
        // ---- P -> LDS: 4 x b64, row q=lr, k=16nb+4lg+{0..3}, XOR swizzled
        half4 p0 = {(_Float16)st[0][0], (_Float16)st[0][1], (_Float16)st[0][2], (_Float16)st[0][3]};
        half4 p1 = {(_Float16)st[1][0], (_Float16)st[1][1], (_Float16)st[1][2], (_Float16)st[1][3]};
        half4 p2 = {(_Float16)st[2][0], (_Float16)st[2][1], (_Float16)st[2][2], (_Float16)st[2][3]};
        half4 p3 = {(_Float16)st[3][0], (_Float16)st[3][1], (_Float16)st[3][2], (_Float16)st[3][3]};
        *(half4*)(pl + pw0) = p0;
        *(half4*)(pl + pw1) = p1;
        *(half4*)(pl + pw2) = p2;
        *(half4*)(pl + pw3) = p3;
        half8 pa0 = *(const half8*)(pl + pr0);
        half8 pa1 = *(const half8*)(pl + pr1);
        // ---- O += P V ----
#pragma unroll
        for (int ob = 0; ob < 4; ++ob) {
            int row = ob * 16 + lr;
            int sw = (row & 7) << 4;
            const char* vp = ldsV + row * 128;
            half8 vf0 = *(const half8*)(vp + ((lg * 16) ^ sw));
            half8 vf1 = *(const half8*)(vp + ((64 + lg * 16) ^ sw));
            oacc[ob] = __builtin_amdgcn_mfma_f32_16x16x32_f16(pa0, vf0, oacc[ob], 0, 0, 0);
            oacc[ob] = __builtin_amdgcn_mfma_f32_16x16x32_f16(pa1, vf1, oacc[ob], 0, 0, 0);
        }
        if (do_stage) __syncthreads();   // full drain (vmcnt 0 + lgkmcnt 0) + barrier
    };

    STAGE(0, 0);
    __syncthreads();
    for (int t = 0; t < 31; ++t) BODY(t, t & 1, true);
    BODY(31, 1, false);   // no stage, no trailing barrier, no DMA at endpgm

    // ---- epilogue: Oatt[n][q][h*64+d] = oacc / l  (l for q=4lg+r via shfl)
    float li0 = __shfl(l_q, lg4 + 0);
    float li1 = __shfl(l_q, lg4 + 1);
    float li2 = __shfl(l_q, lg4 + 2);
    float li3 = __shfl(l_q, lg4 + 3);
    float inv[4] = {1.f / li0, 1.f / li1, 1.f / li2, 1.f / li3};
#pragma unroll
    for (int i = 0; i < 4; ++i) {
        int q = qt * 64 + w * 16 + lg4 + i;
#pragma unroll
        for (int ob = 0; ob < 4; ++ob) {
            int d = ob * 16 + lr;
            Oatt[((size_t)(n * S_LEN + q)) * DM + h * HD + d] = (_Float16)(oacc[ob][i] * inv[i]);
        }
    }
}

// ---------------------------------------------------------------------------
// Projection: out[m][o] = sum_i A[m][i] * W[o][i] + b[o]   (M=4096,O=1024,K=1024)
// XCD swizzle: the 2 ot-slices per XCD (W slice 256 KB) stay L2-resident.
// ---------------------------------------------------------------------------
__global__ __launch_bounds__(256) void k_proj(const _Float16* __restrict__ A,
                                              const _Float16* __restrict__ W,
                                              const float* __restrict__ bias,
                                              float* __restrict__ out) {
    const int id = blockIdx.x;
    const int xcd = id & 7;
    const int sl = id >> 3;            // 0..127
    const int ot = xcd + 8 * (sl & 1); // 0..15
    const int mt = sl >> 1;            // 0..63

    int tid = threadIdx.x, w = tid >> 6, lane = tid & 63;
    int lr = lane & 15, lg = lane >> 4;
    const _Float16* ap = A + (size_t)(mt * 64 + w * 16 + lr) * DM + lg * 8;
    const _Float16* wp = W + (size_t)(ot * 64 + lr) * DM + lg * 8;
    f32x4 zero = {0.f, 0.f, 0.f, 0.f};
    f32x4 acc[4] = {zero, zero, zero, zero};
    for (int ki = 0; ki < DM / 32; ++ki) {
        half8 af = *(const half8*)(ap + ki * 32);
#pragma unroll
        for (int ob = 0; ob < 4; ++ob) {
            half8 bf = *(const half8*)(wp + (size_t)(ob * 16) * DM + ki * 32);
            acc[ob] = __builtin_amdgcn_mfma_f32_16x16x32_f16(af, bf, acc[ob], 0, 0, 0);
        }
    }
#pragma unroll
    for (int ob = 0; ob < 4; ++ob) {
        int o = ot * 64 + ob * 16 + lr;
        float b = bias[o];
#pragma unroll
        for (int i = 0; i < 4; ++i) {
            int m = mt * 64 + w * 16 + lg * 4 + i;
            out[(size_t)m * DM + o] = acc[ob][i] + b;
        }
    }
}

// ---------------------------------------------------------------------------
extern "C" void kernel_launch(void* const* d_in, const int* in_sizes, int n_in,
                              void* d_out, int out_size, void* d_ws, size_t ws_size,
                              hipStream_t stream) {
    const float* Q = (const float*)d_in[0];
    const float* K = (const float*)d_in[1];
    const float* V = (const float*)d_in[2];
    const float* Wo = (const float*)d_in[3];
    const float* bo = (const float*)d_in[4];
    float* out = (float*)d_out;
    char* ws = (char*)d_ws;

    _Float16* Kh = (_Float16*)(ws);                     // 8 MB
    _Float16* Vt = (_Float16*)(ws + (8u << 20));        // 8 MB
    _Float16* Oatt = (_Float16*)(ws + (16u << 20));     // 8 MB
    _Float16* Wh = (_Float16*)(ws + (24u << 20));       // 2 MB

    const int n4 = N_B * S_LEN * DM / 4;                // 1,048,576
    k_regroup<<<n4 / 256, 256, 0, stream>>>(K, Kh, n4);
    k_vt<<<dim3(S_LEN / 64, NH, N_B), 256, 0, stream>>>(V, Vt);
    k_cvt<<<(DM * DM / 4) / 256, 256, 0, stream>>>(Wo, Wh, DM * DM / 4);
    k_attn<<<1024, 256, 0, stream>>>(Q, Kh, Vt, Oatt);
    k_proj<<<1024, 256, 0, stream>>>(Oatt, Wh, bo, out);
}

// Round 7
// 101.342 us; speedup vs baseline: 3.3043x; 1.6006x over previous
//
#include <hip/hip_runtime.h>

typedef _Float16 half8 __attribute__((ext_vector_type(8)));
typedef _Float16 half4 __attribute__((ext_vector_type(4)));
typedef float f32x4 __attribute__((ext_vector_type(4)));

#define N_B 2
#define S_LEN 2048
#define NH 16
#define HD 64
#define DM 1024
#define LOG2E 1.44269504088896f

__device__ __forceinline__ void gload16(const void* g, void* l) {
    __builtin_amdgcn_global_load_lds(
        (const __attribute__((address_space(1))) unsigned int*)g,
        (__attribute__((address_space(3))) unsigned int*)l, 16, 0, 0);
}

__device__ __forceinline__ float fexp2(float x) {
    float r;
    asm("v_exp_f32 %0, %1" : "=v"(r) : "v"(x));
    return r;
}

// ---------------------------------------------------------------------------
// Fused prep (one launch): blocks [0,4096) regroup K -> f16 [n][h][s][d];
// [4096,5120) transpose V -> Vt f16 [n][h][d][s]; [5120,6144) cvt W -> f16.
// ---------------------------------------------------------------------------
__global__ __launch_bounds__(256) void k_prep(const float* __restrict__ K,
                                              const float* __restrict__ V,
                                              const float* __restrict__ Wo,
                                              _Float16* __restrict__ Kh,
                                              _Float16* __restrict__ Vt,
                                              _Float16* __restrict__ Wh) {
    __shared__ _Float16 tile[64][65];
    const int id = blockIdx.x;
    if (id < 4096) {                       // ---- K regroup
        int i = id * 256 + threadIdx.x;
        float4 v = ((const float4*)K)[i];
        int base = i * 4;
        int d = base & 63;
        int h = (base >> 6) & 15;
        int s = (base >> 10) & 2047;
        int n = base >> 21;
        size_t o = ((size_t)((n * NH + h) * S_LEN + s)) * HD + d;
        half4 hv = {(_Float16)v.x, (_Float16)v.y, (_Float16)v.z, (_Float16)v.w};
        *(half4*)(Kh + o) = hv;
    } else if (id < 5120) {                // ---- V transpose
        int b = id - 4096;
        int st = b & 31, h = (b >> 5) & 15, n = b >> 9;
        int c = threadIdx.x & 63, r0 = threadIdx.x >> 6;
#pragma unroll
        for (int i = 0; i < 16; ++i) {
            int r = i * 4 + r0;
            tile[r][c] = (_Float16)V[((size_t)(n * S_LEN) + st * 64 + r) * DM + h * HD + c];
        }
        __syncthreads();
#pragma unroll
        for (int i = 0; i < 16; ++i) {
            int d = i * 4 + r0;
            Vt[((size_t)((n * NH + h) * HD + d)) * S_LEN + st * 64 + c] = tile[c][d];
        }
    } else {                               // ---- W convert
        int i = (id - 5120) * 256 + threadIdx.x;
        float4 v = ((const float4*)Wo)[i];
        half4 hv = {(_Float16)v.x, (_Float16)v.y, (_Float16)v.z, (_Float16)v.w};
        *(half4*)(Wh + (size_t)i * 4) = hv;
    }
}

// ---------------------------------------------------------------------------
// Flash attention, SWAPPED QK^T (lane-local softmax), 2-phase __syncthreads
// pipeline, XCD-swizzled blocks (K/V L2-resident), exp2-domain softmax,
// defer-max (THR=8): skip the rescale chain when the tile max doesn't grow.
// ---------------------------------------------------------------------------
__global__ __launch_bounds__(256) void k_attn(const float* __restrict__ Q,
                                              const _Float16* __restrict__ Kh,
                                              const _Float16* __restrict__ Vth,
                                              _Float16* __restrict__ Oatt) {
    __shared__ _Float16 KT[2][64 * 64];   // 16 KB
    __shared__ _Float16 VS[2][64 * 64];   // 16 KB
    __shared__ _Float16 PL[4][16 * 64];   // 8 KB (per-wave private)

    // XCD swizzle (bijective on 1024 = 8 * 128)
    const int id = blockIdx.x;
    const int xcd = id & 7;
    const int sl = id >> 3;              // 0..127
    const int nh = xcd + 8 * (sl >> 5);  // n*16 + h
    const int qt = sl & 31;              // q tile of 64

    const int tid = threadIdx.x;
    const int w = tid >> 6;
    const int lane = tid & 63;
    const int lr = lane & 15;
    const int lg = lane >> 4;
    const int lg4 = lg * 4;
    const int n = nh >> 4, h = nh & 15;

    const size_t head = (size_t)nh * S_LEN * HD;
    const char* Khead = (const char*)(Kh + head);
    const char* Vhead = (const char*)(Vth + head);

    // ---- Q load fused from original f32 layout, scaled by log2(e)
    const float* qrow = Q + ((size_t)(n * S_LEN) + qt * 64 + w * 16 + lr) * DM + h * HD + lg * 8;
    float4 qa = *(const float4*)(qrow);
    float4 qb = *(const float4*)(qrow + 4);
    float4 qc = *(const float4*)(qrow + 32);
    float4 qd = *(const float4*)(qrow + 36);
    half8 qf0 = {(_Float16)(qa.x * LOG2E), (_Float16)(qa.y * LOG2E),
                 (_Float16)(qa.z * LOG2E), (_Float16)(qa.w * LOG2E),
                 (_Float16)(qb.x * LOG2E), (_Float16)(qb.y * LOG2E),
                 (_Float16)(qb.z * LOG2E), (_Float16)(qb.w * LOG2E)};
    half8 qf1 = {(_Float16)(qc.x * LOG2E), (_Float16)(qc.y * LOG2E),
                 (_Float16)(qc.z * LOG2E), (_Float16)(qc.w * LOG2E),
                 (_Float16)(qd.x * LOG2E), (_Float16)(qd.y * LOG2E),
                 (_Float16)(qd.z * LOG2E), (_Float16)(qd.w * LOG2E)};

    f32x4 zero = {0.f, 0.f, 0.f, 0.f};
    f32x4 oacc[4] = {zero, zero, zero, zero};
    float m_q = -1e30f, l_q = 0.f;   // softmax state (exp2 domain) for query lr

    char* pl = (char*)&PL[w][0];
    const int pmask = (lr & 7) << 4;
    int pw0 = lr * 128 + ((0 * 32 + lg * 8) ^ pmask);
    int pw1 = lr * 128 + ((1 * 32 + lg * 8) ^ pmask);
    int pw2 = lr * 128 + ((2 * 32 + lg * 8) ^ pmask);
    int pw3 = lr * 128 + ((3 * 32 + lg * 8) ^ pmask);
    int pr0 = lr * 128 + ((lg * 16) ^ pmask);
    int pr1 = lr * 128 + ((64 + lg * 16) ^ pmask);

    // staging geometry: wave w stages 2 x 1KB regions of each 8KB tile.
    const int rr = lane >> 3;          // row-within-8
    const int cb = (lane & 7) * 16;    // 16B column block
    const int gcb = cb ^ (rr << 4);    // inverse-swizzled global column

    auto STAGE = [&](int kt, int b) {
#pragma unroll
        for (int j = 0; j < 2; ++j) {
            int row = (w * 2 + j) * 8 + rr;
            gload16(Khead + ((size_t)(kt * 64 + row)) * 128 + gcb,
                    (char*)&KT[b][0] + (w * 2 + j) * 1024);
            gload16(Vhead + (size_t)row * 4096 + (size_t)kt * 128 + gcb,
                    (char*)&VS[b][0] + (w * 2 + j) * 1024);
        }
    };

    auto BODY = [&](int kt, int buf, bool do_stage) {
        if (do_stage) STAGE(kt + 1, buf ^ 1);

        const char* ldsK = (const char*)&KT[buf][0];
        const char* ldsV = (const char*)&VS[buf][0];

        // ---- S^T = K Q^T : lane holds scores for query lr, keys 16nb+4lg+r
        f32x4 st[4] = {zero, zero, zero, zero};
#pragma unroll
        for (int nb = 0; nb < 4; ++nb) {
            int row = nb * 16 + lr;
            int sw = (row & 7) << 4;
            const char* kp = ldsK + row * 128;
            half8 kf0 = *(const half8*)(kp + ((lg * 16) ^ sw));
            half8 kf1 = *(const half8*)(kp + ((64 + lg * 16) ^ sw));
            st[nb] = __builtin_amdgcn_mfma_f32_16x16x32_f16(kf0, qf0, st[nb], 0, 0, 0);
            st[nb] = __builtin_amdgcn_mfma_f32_16x16x32_f16(kf1, qf1, st[nb], 0, 0, 0);
        }
        // ---- lane-local online softmax (exp2 domain), defer-max THR=8 ----
        float t0 = fmaxf(fmaxf(st[0][0], st[0][1]), fmaxf(st[0][2], st[0][3]));
        float t1 = fmaxf(fmaxf(st[1][0], st[1][1]), fmaxf(st[1][2], st[1][3]));
        float t2 = fmaxf(fmaxf(st[2][0], st[2][1]), fmaxf(st[2][2], st[2][3]));
        float t3 = fmaxf(fmaxf(st[3][0], st[3][1]), fmaxf(st[3][2], st[3][3]));
        float tm = fmaxf(fmaxf(t0, t1), fmaxf(t2, t3));
        tm = fmaxf(tm, __shfl_xor(tm, 16));
        tm = fmaxf(tm, __shfl_xor(tm, 32));   // per-query max, uniform over lg
        if (!__all(tm <= m_q + 8.f)) {
            float mn = fmaxf(m_q, tm);
            float sc = fexp2(m_q - mn);
            m_q = mn;
            l_q *= sc;
            float s0 = __shfl(sc, lg4 + 0);
            float s1 = __shfl(sc, lg4 + 1);
            float s2 = __shfl(sc, lg4 + 2);
            float s3 = __shfl(sc, lg4 + 3);
#pragma unroll
            for (int ob = 0; ob < 4; ++ob) {
                oacc[ob][0] *= s0; oacc[ob][1] *= s1;
                oacc[ob][2] *= s2; oacc[ob][3] *= s3;
            }
        }
        float rs = 0.f;
#pragma unroll
        for (int nb = 0; nb < 4; ++nb)
#pragma unroll
            for (int r = 0; r < 4; ++r) {
                float p = fexp2(st[nb][r] - m_q);
                st[nb][r] = p;
                rs += p;
            }
        rs += __shfl_xor(rs, 16);
        rs += __shfl_xor(rs, 32);
        l_q += rs;
        // ---- P -> LDS: 4 x b64, row q=lr, k=16nb+4lg+{0..3}, XOR swizzled
        half4 p0 = {(_Float16)st[0][0], (_Float16)st[0][1], (_Float16)st[0][2], (_Float16)st[0][3]};
        half4 p1 = {(_Float16)st[1][0], (_Float16)st[1][1], (_Float16)st[1][2], (_Float16)st[1][3]};
        half4 p2 = {(_Float16)st[2][0], (_Float16)st[2][1], (_Float16)st[2][2], (_Float16)st[2][3]};
        half4 p3 = {(_Float16)st[3][0], (_Float16)st[3][1], (_Float16)st[3][2], (_Float16)st[3][3]};
        *(half4*)(pl + pw0) = p0;
        *(half4*)(pl + pw1) = p1;
        *(half4*)(pl + pw2) = p2;
        *(half4*)(pl + pw3) = p3;
        half8 pa0 = *(const half8*)(pl + pr0);
        half8 pa1 = *(const half8*)(pl + pr1);
        // ---- O += P V ----
#pragma unroll
        for (int ob = 0; ob < 4; ++ob) {
            int row = ob * 16 + lr;
            int sw = (row & 7) << 4;
            const char* vp = ldsV + row * 128;
            half8 vf0 = *(const half8*)(vp + ((lg * 16) ^ sw));
            half8 vf1 = *(const half8*)(vp + ((64 + lg * 16) ^ sw));
            oacc[ob] = __builtin_amdgcn_mfma_f32_16x16x32_f16(pa0, vf0, oacc[ob], 0, 0, 0);
            oacc[ob] = __builtin_amdgcn_mfma_f32_16x16x32_f16(pa1, vf1, oacc[ob], 0, 0, 0);
        }
        if (do_stage) __syncthreads();   // full drain (vmcnt 0 + lgkmcnt 0) + barrier
    };

    STAGE(0, 0);
    __syncthreads();
    for (int t = 0; t < 31; ++t) BODY(t, t & 1, true);
    BODY(31, 1, false);   // no stage, no trailing barrier, no DMA at endpgm

    // ---- epilogue: Oatt[n][q][h*64+d] = oacc / l  (l for q=4lg+r via shfl)
    float li0 = __shfl(l_q, lg4 + 0);
    float li1 = __shfl(l_q, lg4 + 1);
    float li2 = __shfl(l_q, lg4 + 2);
    float li3 = __shfl(l_q, lg4 + 3);
    float inv[4] = {1.f / li0, 1.f / li1, 1.f / li2, 1.f / li3};
#pragma unroll
    for (int i = 0; i < 4; ++i) {
        int q = qt * 64 + w * 16 + lg4 + i;
#pragma unroll
        for (int ob = 0; ob < 4; ++ob) {
            int d = ob * 16 + lr;
            Oatt[((size_t)(n * S_LEN + q)) * DM + h * HD + d] = (_Float16)(oacc[ob][i] * inv[i]);
        }
    }
}

// ---------------------------------------------------------------------------
// Projection GEMM, m97-style: 128x128 tile, BK=64, LDS double-buffered via
// gload16 (inverse-swizzled source, linear dest), 4 waves a 64x64 output.
// Grid 256 = 8 ot-strips x 32 mt; ot pinned per XCD (W strip L2-resident).
// ---------------------------------------------------------------------------
__global__ __launch_bounds__(256) void k_proj(const _Float16* __restrict__ A,
                                              const _Float16* __restrict__ W,
                                              const float* __restrict__ bias,
                                              float* __restrict__ out) {
    __shared__ _Float16 As[2][128 * 64];   // 16 KB each
    __shared__ _Float16 Ws[2][128 * 64];

    const int id = blockIdx.x;
    const int ot = id & 7;     // O strip of 128
    const int mt = id >> 3;    // M strip of 128 (0..31)
    const int tid = threadIdx.x;
    const int w = tid >> 6;
    const int lane = tid & 63;
    const int lr = lane & 15, lg = lane >> 4;
    const int wm = (w >> 1) * 64, wn = (w & 1) * 64;

    const int rr = lane >> 3;
    const int cb = (lane & 7) * 16;
    const int gcb = cb ^ (rr << 4);

    const char* Abase = (const char*)(A + (size_t)(mt * 128) * DM);
    const char* Wbase = (const char*)(W + (size_t)(ot * 128) * DM);

    auto STAGE = [&](int kt, int b) {
#pragma unroll
        for (int r = 0; r < 4; ++r) {
            int row = r * 32 + w * 8 + rr;
            gload16(Abase + (size_t)row * 2048 + kt * 128 + gcb,
                    (char*)&As[b][0] + (r * 32 + w * 8) * 128);
            gload16(Wbase + (size_t)row * 2048 + kt * 128 + gcb,
                    (char*)&Ws[b][0] + (r * 32 + w * 8) * 128);
        }
    };

    f32x4 zero = {0.f, 0.f, 0.f, 0.f};
    f32x4 acc[4][4];
#pragma unroll
    for (int mi = 0; mi < 4; ++mi)
#pragma unroll
        for (int ni = 0; ni < 4; ++ni) acc[mi][ni] = zero;

    auto COMPUTE = [&](int b) {
        const char* ldsA = (const char*)&As[b][0];
        const char* ldsW = (const char*)&Ws[b][0];
        half8 af[4][2], wf[4][2];
#pragma unroll
        for (int mi = 0; mi < 4; ++mi) {
            int row = wm + mi * 16 + lr;
            int sw = (row & 7) << 4;
            const char* p = ldsA + row * 128;
            af[mi][0] = *(const half8*)(p + ((lg * 16) ^ sw));
            af[mi][1] = *(const half8*)(p + ((64 + lg * 16) ^ sw));
        }
#pragma unroll
        for (int ni = 0; ni < 4; ++ni) {
            int row = wn + ni * 16 + lr;
            int sw = (row & 7) << 4;
            const char* p = ldsW + row * 128;
            wf[ni][0] = *(const half8*)(p + ((lg * 16) ^ sw));
            wf[ni][1] = *(const half8*)(p + ((64 + lg * 16) ^ sw));
        }
#pragma unroll
        for (int mi = 0; mi < 4; ++mi)
#pragma unroll
            for (int ni = 0; ni < 4; ++ni) {
                acc[mi][ni] = __builtin_amdgcn_mfma_f32_16x16x32_f16(af[mi][0], wf[ni][0], acc[mi][ni], 0, 0, 0);
                acc[mi][ni] = __builtin_amdgcn_mfma_f32_16x16x32_f16(af[mi][1], wf[ni][1], acc[mi][ni], 0, 0, 0);
            }
    };

    STAGE(0, 0);
    __syncthreads();
    for (int kt = 0; kt < 15; ++kt) {
        STAGE(kt + 1, (kt & 1) ^ 1);
        COMPUTE(kt & 1);
        __syncthreads();
    }
    COMPUTE(1);   // kt=15, no stage -> no DMA outstanding at endpgm

    // epilogue: C row = m (A dim), col = o (W dim)
#pragma unroll
    for (int ni = 0; ni < 4; ++ni) {
        int o = ot * 128 + wn + ni * 16 + lr;
        float b = bias[o];
#pragma unroll
        for (int mi = 0; mi < 4; ++mi)
#pragma unroll
            for (int i = 0; i < 4; ++i) {
                int m = mt * 128 + wm + mi * 16 + lg * 4 + i;
                out[(size_t)m * DM + o] = acc[mi][ni][i] + b;
            }
    }
}

// ---------------------------------------------------------------------------
extern "C" void kernel_launch(void* const* d_in, const int* in_sizes, int n_in,
                              void* d_out, int out_size, void* d_ws, size_t ws_size,
                              hipStream_t stream) {
    const float* Q = (const float*)d_in[0];
    const float* K = (const float*)d_in[1];
    const float* V = (const float*)d_in[2];
    const float* Wo = (const float*)d_in[3];
    const float* bo = (const float*)d_in[4];
    float* out = (float*)d_out;
    char* ws = (char*)d_ws;

    _Float16* Kh = (_Float16*)(ws);                     // 8 MB
    _Float16* Vt = (_Float16*)(ws + (8u << 20));        // 8 MB
    _Float16* Oatt = (_Float16*)(ws + (16u << 20));     // 8 MB
    _Float16* Wh = (_Float16*)(ws + (24u << 20));       // 2 MB

    k_prep<<<6144, 256, 0, stream>>>(K, V, Wo, Kh, Vt, Wh);
    k_attn<<<1024, 256, 0, stream>>>(Q, Kh, Vt, Oatt);
    k_proj<<<256, 256, 0, stream>>>(Oatt, Wh, bo, out);
}